// Round 2
// baseline (1507.117 us; speedup 1.0000x reference)
//
#include <hip/hip_runtime.h>
#include <hip/hip_bf16.h>
#include <stdint.h>

typedef __attribute__((ext_vector_type(8))) short short8;
typedef __attribute__((ext_vector_type(4))) float floatx4;

#define NE 2048
#define NH 16
#define HD 128
#define SAH 12
#define BB 4
#define TT 2048
#define MM (BB*TT)
#define NQKV (3*NE)

__device__ __forceinline__ ushort f2bfu(float f){
    __hip_bfloat16 h = __float2bfloat16(f);
    union { __hip_bfloat16 h; ushort u; } c; c.h = h; return c.u;
}

// ---------------- fp32 -> bf16 conversion ----------------
__global__ void cvt_f32_bf16(const float* __restrict__ s, ushort* __restrict__ d, int n4){
    const int stride = gridDim.x * blockDim.x;
    for (int i = blockIdx.x*blockDim.x + threadIdx.x; i < n4; i += stride){
        const float4 v = ((const float4*)s)[i];
        ushort4 o;
        o.x = f2bfu(v.x); o.y = f2bfu(v.y); o.z = f2bfu(v.z); o.w = f2bfu(v.w);
        ((ushort4*)d)[i] = o;
    }
}

// ---------------- BT GEMM: C[M,N] = A[M,K] * B[N,K]^T (bf16 in, f32 acc) ----------------
// MODE 0: write f32 C row-major.
// MODE 1: write bf16 C (qkv scratch) + scatter f32 k/v to cur_k/cur_v head layout.
template<int MODE>
__global__ __launch_bounds__(256) void gemm_bt(
    const ushort* __restrict__ A, const ushort* __restrict__ Bw,
    ushort* __restrict__ Cbf, float* __restrict__ Cf,
    float* __restrict__ outK, float* __restrict__ outV,
    int N, int K)
{
    __shared__ __align__(16) ushort Alds[128*32];
    __shared__ __align__(16) ushort Blds[128*32];
    const int tid  = threadIdx.x;
    const int wave = tid >> 6, lane = tid & 63;
    const int m0 = blockIdx.y << 7, n0 = blockIdx.x << 7;
    const int wr = wave >> 1, wc = wave & 1;

    floatx4 acc[4][4];
#pragma unroll
    for (int i=0;i<4;i++)
#pragma unroll
        for (int j=0;j<4;j++) acc[i][j] = (floatx4){0.f,0.f,0.f,0.f};

    const int sr = lane >> 2, sc = (lane & 3) << 3;
    const ushort* gA = A  + (size_t)(m0 + wave*32 + sr)*K + sc;
    const ushort* gB = Bw + (size_t)(n0 + wave*32 + sr)*K + sc;
    ushort* lA = Alds + wave*32*32;
    ushort* lB = Blds + wave*32*32;
    const int fr = lane & 15, fo = (lane >> 4) << 3;

    for (int kt = 0; kt < K; kt += 32){
        __builtin_amdgcn_global_load_lds((__attribute__((address_space(1))) void*)(gA + kt),
                                         (__attribute__((address_space(3))) void*)lA, 16, 0, 0);
        __builtin_amdgcn_global_load_lds((__attribute__((address_space(1))) void*)(gA + kt + (size_t)16*K),
                                         (__attribute__((address_space(3))) void*)(lA + 16*32), 16, 0, 0);
        __builtin_amdgcn_global_load_lds((__attribute__((address_space(1))) void*)(gB + kt),
                                         (__attribute__((address_space(3))) void*)lB, 16, 0, 0);
        __builtin_amdgcn_global_load_lds((__attribute__((address_space(1))) void*)(gB + kt + (size_t)16*K),
                                         (__attribute__((address_space(3))) void*)(lB + 16*32), 16, 0, 0);
        __syncthreads();
        short8 af[4], bfb[4];
#pragma unroll
        for (int i=0;i<4;i++) af[i]  = *(const short8*)(Alds + (wr*64 + i*16 + fr)*32 + fo);
#pragma unroll
        for (int j=0;j<4;j++) bfb[j] = *(const short8*)(Blds + (wc*64 + j*16 + fr)*32 + fo);
#pragma unroll
        for (int i=0;i<4;i++)
#pragma unroll
            for (int j=0;j<4;j++)
                acc[i][j] = __builtin_amdgcn_mfma_f32_16x16x32_bf16(af[i], bfb[j], acc[i][j], 0, 0, 0);
        __syncthreads();
    }

#pragma unroll
    for (int i=0;i<4;i++){
#pragma unroll
        for (int j=0;j<4;j++){
#pragma unroll
            for (int r=0;r<4;r++){
                const int row = m0 + wr*64 + i*16 + ((lane>>4)<<2) + r;
                const int col = n0 + wc*64 + j*16 + fr;
                const float v = acc[i][j][r];
                if (MODE == 0){
                    Cf[(size_t)row*N + col] = v;
                } else {
                    Cbf[(size_t)row*NQKV + col] = f2bfu(v);
                    if (col >= NE){
                        const int b = row >> 11, t = row & (TT-1);
                        const int hd = (col - NE) & (NE-1);
                        float* dst = (col >= 2*NE) ? outV : outK;
                        dst[(((size_t)b*NH + (hd>>7))*TT + t)*HD + (hd & 127)] = v;
                    }
                }
            }
        }
    }
}

// ---------------- Flash attention ----------------
// Block: 256 threads = 4 waves; 64 q-rows/block (16 per wave); KBLK=32.
// h < 12: causal self-attn, K/V from qkv scratch (bf16).
// h >= 12: non-causal cross-attn, K/V from prev_k{h-12}/prev_v{h-12} head h (fp32).
__global__ __launch_bounds__(256) void attn(
    const ushort* __restrict__ qkv, ushort* __restrict__ Y,
    const float* __restrict__ pk0, const float* __restrict__ pv0,
    const float* __restrict__ pk1, const float* __restrict__ pv1,
    const float* __restrict__ pk2, const float* __restrict__ pv2,
    const float* __restrict__ pk3, const float* __restrict__ pv3)
{
    __shared__ __align__(16) ushort Klds[32*136];   // [kpos][d] pad->136
    __shared__ __align__(16) ushort Vt[128*40];     // [d][kpos] pad->40
    __shared__ __align__(16) ushort Plds[4][16*40]; // per-wave [qrow][kpos] pad->40

    const int tid  = threadIdx.x;
    const int wave = tid >> 6, lane = tid & 63;
    const int bid = blockIdx.x;
    const int qt = bid & 31;
    const int h  = (bid >> 5) & 15;
    const int b  = bid >> 9;
    const int q0 = qt << 6;
    const bool causal = (h < SAH);

    const float* pkc = nullptr; const float* pvc = nullptr;
    if (!causal){
        const int i = h - SAH;
        if      (i==0){ pkc=pk0; pvc=pv0; }
        else if (i==1){ pkc=pk1; pvc=pv1; }
        else if (i==2){ pkc=pk2; pvc=pv2; }
        else          { pkc=pk3; pvc=pv3; }
        const size_t off = ((size_t)b*NH + h)*(size_t)TT*HD;
        pkc += off; pvc += off;
    }

    const int fr = lane & 15, fo = (lane>>4) << 3;
    const int wq = q0 + wave*16;

    // Q fragments (held in registers for the whole block)
    short8 qf[4];
    {
        const ushort* qp = qkv + (size_t)(b*TT + wq + fr)*NQKV + h*HD + fo;
#pragma unroll
        for (int kk=0;kk<4;kk++) qf[kk] = *(const short8*)(qp + kk*32);
    }

    floatx4 o[8];
#pragma unroll
    for (int dt=0; dt<8; dt++) o[dt] = (floatx4){0.f,0.f,0.f,0.f};
    float m_run[4] = {-1e30f,-1e30f,-1e30f,-1e30f};
    float l_run[4] = {0.f,0.f,0.f,0.f};

    const int srr = tid >> 3;          // staging row 0..31
    const int sds = (tid & 7) << 4;    // staging d-offset (16 elems per thread)
    const int nkb = causal ? ((q0 >> 5) + 2) : (TT/32);

    for (int kb = 0; kb < nkb; kb++){
        const int kstart = kb << 5;
        short8 k0v, k1v, v0v, v1v;
        if (causal){
            const ushort* sk = qkv + (size_t)(b*TT + kstart + srr)*NQKV + NE + h*HD + sds;
            const ushort* sv = sk + NE;
            k0v = *(const short8*)sk;     k1v = *(const short8*)(sk+8);
            v0v = *(const short8*)sv;     v1v = *(const short8*)(sv+8);
        } else {
            const float* sk = pkc + (size_t)(kstart + srr)*HD + sds;
            const float* sv = pvc + (size_t)(kstart + srr)*HD + sds;
            ushort* kp = (ushort*)&k0v;  ushort* kp1 = (ushort*)&k1v;
            ushort* vp = (ushort*)&v0v;  ushort* vp1 = (ushort*)&v1v;
#pragma unroll
            for (int e=0;e<8;e++){ kp[e]  = f2bfu(sk[e]);   vp[e]  = f2bfu(sv[e]); }
#pragma unroll
            for (int e=0;e<8;e++){ kp1[e] = f2bfu(sk[8+e]); vp1[e] = f2bfu(sv[8+e]); }
        }
        *(short8*)(Klds + srr*136 + sds)     = k0v;
        *(short8*)(Klds + srr*136 + sds + 8) = k1v;
        {
            const ushort* vp  = (const ushort*)&v0v;
            const ushort* vp1 = (const ushort*)&v1v;
#pragma unroll
            for (int e=0;e<8;e++) Vt[(sds+e)*40 + srr]   = vp[e];
#pragma unroll
            for (int e=0;e<8;e++) Vt[(sds+8+e)*40 + srr] = vp1[e];
        }
        __syncthreads();

        if (!causal || kstart <= wq + 15){
            // QK^T
            floatx4 s0 = (floatx4){0.f,0.f,0.f,0.f}, s1 = (floatx4){0.f,0.f,0.f,0.f};
#pragma unroll
            for (int kk=0;kk<4;kk++){
                short8 kb0 = *(const short8*)(Klds + fr*136       + kk*32 + fo);
                short8 kb1 = *(const short8*)(Klds + (16+fr)*136  + kk*32 + fo);
                s0 = __builtin_amdgcn_mfma_f32_16x16x32_bf16(qf[kk], kb0, s0, 0,0,0);
                s1 = __builtin_amdgcn_mfma_f32_16x16x32_bf16(qf[kk], kb1, s1, 0,0,0);
            }
            const float scale = 0.08838834764831845f; // 1/sqrt(128)
            ushort* Pw = Plds[wave];
#pragma unroll
            for (int r=0;r<4;r++){
                const int qpos = wq + ((lane>>4)<<2) + r;
                float x0 = s0[r]*scale, x1 = s1[r]*scale;
                if (causal){
                    if (kstart + fr      > qpos) x0 = -1e30f;
                    if (kstart + 16 + fr > qpos) x1 = -1e30f;
                }
                float mx = fmaxf(x0, x1);
#pragma unroll
                for (int mmk=1; mmk<16; mmk<<=1) mx = fmaxf(mx, __shfl_xor(mx, mmk));
                mx = fmaxf(mx, m_run[r]);
                const float alpha = __expf(m_run[r] - mx);
                m_run[r] = mx;
                const float p0 = __expf(x0 - mx), p1 = __expf(x1 - mx);
                float ps = p0 + p1;
#pragma unroll
                for (int mmk=1; mmk<16; mmk<<=1) ps += __shfl_xor(ps, mmk);
                l_run[r] = l_run[r]*alpha + ps;
#pragma unroll
                for (int dt=0;dt<8;dt++) o[dt][r] *= alpha;
                const int prow = ((lane>>4)<<2) + r;
                Pw[prow*40 + fr]      = f2bfu(p0);
                Pw[prow*40 + 16 + fr] = f2bfu(p1);
            }
            asm volatile("s_waitcnt lgkmcnt(0)" ::: "memory");
            short8 pf = *(const short8*)(Pw + fr*40 + fo);
#pragma unroll
            for (int dt=0;dt<8;dt++){
                short8 vf = *(const short8*)(Vt + (dt*16 + fr)*40 + fo);
                o[dt] = __builtin_amdgcn_mfma_f32_16x16x32_bf16(pf, vf, o[dt], 0,0,0);
            }
        }
        __syncthreads();
    }

    float inv[4];
#pragma unroll
    for (int r=0;r<4;r++) inv[r] = 1.0f / l_run[r];
#pragma unroll
    for (int dt=0;dt<8;dt++){
#pragma unroll
        for (int r=0;r<4;r++){
            const int q = wq + ((lane>>4)<<2) + r;
            const int d = dt*16 + fr;
            Y[(size_t)(b*TT + q)*NE + h*HD + d] = f2bfu(o[dt][r]*inv[r]);
        }
    }
}

// ---------------- launch ----------------
extern "C" void kernel_launch(void* const* d_in, const int* in_sizes, int n_in,
                              void* d_out, int out_size, void* d_ws, size_t ws_size,
                              hipStream_t stream)
{
    const float* x      = (const float*)d_in[0];
    const float* w_attn = (const float*)d_in[1];
    const float* w_proj = (const float*)d_in[2];
    const float* pk0 = (const float*)d_in[3];
    const float* pv0 = (const float*)d_in[4];
    const float* pk1 = (const float*)d_in[5];
    const float* pv1 = (const float*)d_in[6];
    const float* pk2 = (const float*)d_in[7];
    const float* pv2 = (const float*)d_in[8];
    const float* pk3 = (const float*)d_in[9];
    const float* pv3 = (const float*)d_in[10];

    float* outY = (float*)d_out;
    float* outK = outY + (size_t)MM*NE;
    float* outV = outK + (size_t)MM*NE;

    char* w = (char*)d_ws;
    ushort* x_bf   = (ushort*)(w);              //  33,554,432 B
    ushort* wa_bf  = (ushort*)(w + 33554432);   //  25,165,824 B
    ushort* wp_bf  = (ushort*)(w + 58720256);   //   8,388,608 B
    ushort* qkv_bf = (ushort*)(w + 67108864);   // 100,663,296 B
    ushort* y_bf   = (ushort*)(w + 167772160);  //  33,554,432 B  (total 192 MiB)

    cvt_f32_bf16<<<2048, 256, 0, stream>>>(x,      x_bf,  MM*NE/4);
    cvt_f32_bf16<<<2048, 256, 0, stream>>>(w_attn, wa_bf, NQKV*NE/4);
    cvt_f32_bf16<<<1024, 256, 0, stream>>>(w_proj, wp_bf, NE*NE/4);

    gemm_bt<1><<<dim3(NQKV/128, MM/128), 256, 0, stream>>>(
        x_bf, wa_bf, qkv_bf, nullptr, outK, outV, NQKV, NE);

    attn<<<BB*NH*(TT/64), 256, 0, stream>>>(
        qkv_bf, y_bf, pk0, pv0, pk1, pv1, pk2, pv2, pk3, pv3);

    gemm_bt<0><<<dim3(NE/128, MM/128), 256, 0, stream>>>(
        y_bf, wp_bf, nullptr, outY, nullptr, nullptr, NE, NE);
}

// Round 4
// 1253.299 us; speedup vs baseline: 1.2025x; 1.2025x over previous
//
#include <hip/hip_runtime.h>
#include <hip/hip_bf16.h>
#include <stdint.h>

typedef __attribute__((ext_vector_type(8))) short short8;
typedef __attribute__((ext_vector_type(4))) float floatx4;

#define NE 2048
#define NH 16
#define HD 128
#define SAH 12
#define BB 4
#define TT 2048
#define MM (BB*TT)
#define NQKV (3*NE)
#define KBLK 64

__device__ __forceinline__ ushort f2bfu(float f){
    __hip_bfloat16 h = __float2bfloat16(f);
    union { __hip_bfloat16 h; ushort u; } c; c.h = h; return c.u;
}

// 16B-block XOR swizzle: spreads row r's blocks across bank quads.
__device__ __forceinline__ int swz(int r){ return (((r>>3)&3)<<1) ^ (r&7); }

// ---------------- fp32 -> bf16 conversion ----------------
__global__ void cvt_f32_bf16(const float* __restrict__ s, ushort* __restrict__ d, int n4){
    const int stride = gridDim.x * blockDim.x;
    for (int i = blockIdx.x*blockDim.x + threadIdx.x; i < n4; i += stride){
        const float4 v = ((const float4*)s)[i];
        ushort4 o;
        o.x = f2bfu(v.x); o.y = f2bfu(v.y); o.z = f2bfu(v.z); o.w = f2bfu(v.w);
        ((ushort4*)d)[i] = o;
    }
}

// ---------------- cross-head K slices -> compact bf16 [b*4+i][t][d] ----------------
__global__ void kc_cvt(const float* __restrict__ pk0, const float* __restrict__ pk1,
                       const float* __restrict__ pk2, const float* __restrict__ pk3,
                       ushort* __restrict__ kc){
    const int bh2 = blockIdx.y;            // b*4+i
    const int i = bh2 & 3, b = bh2 >> 2;
    const float* src = (i==0?pk0 : i==1?pk1 : i==2?pk2 : pk3)
                     + (size_t)(b*NH + SAH + i)*TT*HD;
    const int idx = (blockIdx.x*256 + threadIdx.x)*8;
    float4 a0 = *(const float4*)(src + idx);
    float4 a1 = *(const float4*)(src + idx + 4);
    ushort* dst = kc + (size_t)bh2*TT*HD + idx;
    ushort4 o0, o1;
    o0.x=f2bfu(a0.x); o0.y=f2bfu(a0.y); o0.z=f2bfu(a0.z); o0.w=f2bfu(a0.w);
    o1.x=f2bfu(a1.x); o1.y=f2bfu(a1.y); o1.z=f2bfu(a1.z); o1.w=f2bfu(a1.w);
    *(ushort4*)dst = o0; *(ushort4*)(dst+4) = o1;
}

// ---------------- cross-head V slices -> bf16 V^T [b*4+i][d][t] ----------------
__global__ void vt_cross_k(const float* __restrict__ pv0, const float* __restrict__ pv1,
                           const float* __restrict__ pv2, const float* __restrict__ pv3,
                           ushort* __restrict__ vtC){
    const int bh2 = blockIdx.z;            // b*4+i
    const int i = bh2 & 3, b = bh2 >> 2;
    const int db = blockIdx.y;             // 0..15 (8 d each)
    const int t  = blockIdx.x*256 + threadIdx.x;
    const float* src = (i==0?pv0 : i==1?pv1 : i==2?pv2 : pv3)
                     + ((size_t)(b*NH + SAH + i)*TT + t)*HD + db*8;
    float4 a0 = *(const float4*)src;
    float4 a1 = *(const float4*)(src + 4);
    float vals[8] = {a0.x,a0.y,a0.z,a0.w,a1.x,a1.y,a1.z,a1.w};
#pragma unroll
    for (int e=0;e<8;e++)
        vtC[((size_t)bh2*HD + db*8 + e)*TT + t] = f2bfu(vals[e]);
}

// ---------------- self-head V (from qkv scratch) -> bf16 V^T [b*12+h][d][t] ----------------
__global__ void vt_self_k(const ushort* __restrict__ qkv, ushort* __restrict__ vtS){
    const int bh = blockIdx.z;             // b*12+h
    const int b = bh/12, h = bh%12;
    const int db = blockIdx.y;             // 0..15
    const int t  = blockIdx.x*256 + threadIdx.x;
    const ushort* src = qkv + (size_t)(b*TT + t)*NQKV + 2*NE + h*HD + db*8;
    short8 v = *(const short8*)src;
    const ushort* vp = (const ushort*)&v;
#pragma unroll
    for (int e=0;e<8;e++)
        vtS[((size_t)bh*HD + db*8 + e)*TT + t] = vp[e];
}

// ---------------- BT GEMM: C[M,N] = A[M,K] * B[N,K]^T (bf16 in, f32 acc) ----------------
template<int MODE>
__global__ __launch_bounds__(256) void gemm_bt(
    const ushort* __restrict__ A, const ushort* __restrict__ Bw,
    ushort* __restrict__ Cbf, float* __restrict__ Cf,
    float* __restrict__ outK, float* __restrict__ outV,
    int N, int K)
{
    __shared__ __align__(16) ushort Alds[128*32];
    __shared__ __align__(16) ushort Blds[128*32];
    const int tid  = threadIdx.x;
    const int wave = tid >> 6, lane = tid & 63;
    const int m0 = blockIdx.y << 7, n0 = blockIdx.x << 7;
    const int wr = wave >> 1, wc = wave & 1;

    floatx4 acc[4][4];
#pragma unroll
    for (int i=0;i<4;i++)
#pragma unroll
        for (int j=0;j<4;j++) acc[i][j] = (floatx4){0.f,0.f,0.f,0.f};

    const int sr = lane >> 2, sc = (lane & 3) << 3;
    const ushort* gA = A  + (size_t)(m0 + wave*32 + sr)*K + sc;
    const ushort* gB = Bw + (size_t)(n0 + wave*32 + sr)*K + sc;
    ushort* lA = Alds + wave*32*32;
    ushort* lB = Blds + wave*32*32;
    const int fr = lane & 15, fo = (lane >> 4) << 3;

    for (int kt = 0; kt < K; kt += 32){
        __builtin_amdgcn_global_load_lds((__attribute__((address_space(1))) void*)(gA + kt),
                                         (__attribute__((address_space(3))) void*)lA, 16, 0, 0);
        __builtin_amdgcn_global_load_lds((__attribute__((address_space(1))) void*)(gA + kt + (size_t)16*K),
                                         (__attribute__((address_space(3))) void*)(lA + 16*32), 16, 0, 0);
        __builtin_amdgcn_global_load_lds((__attribute__((address_space(1))) void*)(gB + kt),
                                         (__attribute__((address_space(3))) void*)lB, 16, 0, 0);
        __builtin_amdgcn_global_load_lds((__attribute__((address_space(1))) void*)(gB + kt + (size_t)16*K),
                                         (__attribute__((address_space(3))) void*)(lB + 16*32), 16, 0, 0);
        __syncthreads();
        short8 af[4], bfb[4];
#pragma unroll
        for (int i=0;i<4;i++) af[i]  = *(const short8*)(Alds + (wr*64 + i*16 + fr)*32 + fo);
#pragma unroll
        for (int j=0;j<4;j++) bfb[j] = *(const short8*)(Blds + (wc*64 + j*16 + fr)*32 + fo);
#pragma unroll
        for (int i=0;i<4;i++)
#pragma unroll
            for (int j=0;j<4;j++)
                acc[i][j] = __builtin_amdgcn_mfma_f32_16x16x32_bf16(af[i], bfb[j], acc[i][j], 0, 0, 0);
        __syncthreads();
    }

#pragma unroll
    for (int i=0;i<4;i++){
#pragma unroll
        for (int j=0;j<4;j++){
#pragma unroll
            for (int r=0;r<4;r++){
                const int row = m0 + wr*64 + i*16 + ((lane>>4)<<2) + r;
                const int col = n0 + wc*64 + j*16 + fr;
                const float v = acc[i][j][r];
                if (MODE == 0){
                    Cf[(size_t)row*N + col] = v;
                } else {
                    Cbf[(size_t)row*NQKV + col] = f2bfu(v);
                    if (col >= NE){
                        const int b = row >> 11, t = row & (TT-1);
                        const int hd = (col - NE) & (NE-1);
                        float* dst = (col >= 2*NE) ? outV : outK;
                        dst[(((size_t)b*NH + (hd>>7))*TT + t)*HD + (hd & 127)] = v;
                    }
                }
            }
        }
    }
}

// ---------------- Flash attention v2: swizzled LDS, KBLK=64, global_load_lds staging ----
// 256 threads = 4 waves, 64 q-rows/block (16 per wave).
// K tile [64 k][128 d], V^T tile [128 d][64 k], P per-wave [16 q][64 k] — all bf16,
// all rows XOR-block-swizzled by swz(row) so every ds access is conflict-free.
__global__ __launch_bounds__(256) void attn2(
    const ushort* __restrict__ qkv, const ushort* __restrict__ kc,
    const ushort* __restrict__ vtS, const ushort* __restrict__ vtC,
    ushort* __restrict__ Y)
{
    __shared__ __align__(16) ushort Klds[64*128];
    __shared__ __align__(16) ushort Vlds[128*64];
    __shared__ __align__(16) ushort Plds[4][16*64];

    const int tid  = threadIdx.x;
    const int wave = tid >> 6, lane = tid & 63;
    const int fr = lane & 15, g = lane >> 4;
    const int bid = blockIdx.x;
    const int qt = bid & 31;
    const int h  = (bid >> 5) & 15;
    const int b  = bid >> 9;
    const int q0 = qt << 6;
    const bool causal = (h < SAH);

    const ushort* Kbase; size_t strideK; const ushort* Vbase;
    if (causal){
        Kbase = qkv + (size_t)b*TT*NQKV + NE + h*HD;  strideK = NQKV;
        Vbase = vtS + (size_t)(b*12 + h)*HD*TT;
    } else {
        const int i = h - SAH;
        Kbase = kc  + (size_t)(b*4 + i)*TT*HD;        strideK = HD;
        Vbase = vtC + (size_t)(b*4 + i)*HD*TT;
    }
    const int wq = q0 + wave*16;

    // Q fragments (row = wq+fr, k = kk*32 + g*8 + e)
    short8 qf[4];
    {
        const ushort* qp = qkv + (size_t)(b*TT + wq + fr)*NQKV + h*HD + g*8;
#pragma unroll
        for (int kk=0;kk<4;kk++) qf[kk] = *(const short8*)(qp + kk*32);
    }

    // staging per-lane offsets (kstart-independent parts)
    size_t koff[4], voff[4];
#pragma unroll
    for (int i=0;i<4;i++){
        const int row = wave*16 + i*4 + (lane>>4);          // K row 0..63
        koff[i] = (size_t)row*strideK + (size_t)(((lane & 15) ^ swz(row)) << 3);
    }
#pragma unroll
    for (int i=0;i<4;i++){
        const int row = wave*32 + i*8 + (lane>>3);          // V^T row 0..127
        voff[i] = (size_t)row*TT + (size_t)(((lane & 7) ^ swz(row)) << 3);
    }

    floatx4 o[8];
#pragma unroll
    for (int dt=0; dt<8; dt++) o[dt] = (floatx4){0.f,0.f,0.f,0.f};
    float m_run[4] = {-1e30f,-1e30f,-1e30f,-1e30f};
    float l_run[4] = {0.f,0.f,0.f,0.f};

    const float scale = 0.08838834764831845f; // 1/sqrt(128)
    const int nkb = causal ? (qt + 1) : (TT/KBLK);

    for (int kb = 0; kb < nkb; kb++){
        const int kstart = kb << 6;
        // stage K tile (16 KB) + V^T tile (16 KB) via global_load_lds, pre-swizzled src
#pragma unroll
        for (int i=0;i<4;i++)
            __builtin_amdgcn_global_load_lds(
                (__attribute__((address_space(1))) void*)(Kbase + (size_t)kstart*strideK + koff[i]),
                (__attribute__((address_space(3))) void*)(Klds + (wave*4+i)*512), 16, 0, 0);
#pragma unroll
        for (int i=0;i<4;i++)
            __builtin_amdgcn_global_load_lds(
                (__attribute__((address_space(1))) void*)(Vbase + (size_t)kstart + voff[i]),
                (__attribute__((address_space(3))) void*)(Vlds + (wave*4+i)*512), 16, 0, 0);
        __syncthreads();

        // QK^T: S[q 16][k' 64] in 4 accs (acc j: k' in [16j,16j+16))
        floatx4 sA[4];
#pragma unroll
        for (int j=0;j<4;j++) sA[j] = (floatx4){0.f,0.f,0.f,0.f};
#pragma unroll
        for (int j=0;j<4;j++){
            const int row = 16*j + fr;
            const int sR = swz(row);
#pragma unroll
            for (int kk=0;kk<4;kk++){
                const short8 kf = *(const short8*)(Klds + row*128 + (((kk*4+g) ^ sR)<<3));
                sA[j] = __builtin_amdgcn_mfma_f32_16x16x32_bf16(qf[kk], kf, sA[j], 0,0,0);
            }
        }

        // online softmax (rows q = wq + 4g + r; cols k' = 16j + fr across 16 lanes)
        const bool domask = causal && (kstart + 63 > wq);
        ushort* Pw = Plds[wave];
#pragma unroll
        for (int r=0;r<4;r++){
            float xs[4];
#pragma unroll
            for (int j=0;j<4;j++) xs[j] = sA[j][r]*scale;
            if (domask){
                const int qpos = wq + 4*g + r;
#pragma unroll
                for (int j=0;j<4;j++)
                    if (kstart + 16*j + fr > qpos) xs[j] = -1e30f;
            }
            float mx = fmaxf(fmaxf(xs[0],xs[1]), fmaxf(xs[2],xs[3]));
#pragma unroll
            for (int d=1; d<16; d<<=1) mx = fmaxf(mx, __shfl_xor(mx, d));
            const float mn = fmaxf(m_run[r], mx);
            const float alpha = __expf(m_run[r] - mn);
            m_run[r] = mn;
            float p[4]; float ps = 0.f;
#pragma unroll
            for (int j=0;j<4;j++){ p[j] = __expf(xs[j]-mn); ps += p[j]; }
#pragma unroll
            for (int d=1; d<16; d<<=1) ps += __shfl_xor(ps, d);
            l_run[r] = l_run[r]*alpha + ps;
#pragma unroll
            for (int dt=0;dt<8;dt++) o[dt][r] *= alpha;
            const int q = 4*g + r;
            const int sq = swz(q);
#pragma unroll
            for (int j=0;j<4;j++)
                Pw[q*64 + (((2*j + (fr>>3)) ^ sq)<<3) + (fr&7)] = f2bfu(p[j]);
        }

        // PV: O[q 16][d 128] += P[16][64] * V[64][128]
        short8 pa[2];
        {
            const int sF = swz(fr);
#pragma unroll
            for (int ks=0;ks<2;ks++)
                pa[ks] = *(const short8*)(Pw + fr*64 + (((ks*4+g) ^ sF)<<3));
        }
#pragma unroll
        for (int dt=0;dt<8;dt++){
            const int row = dt*16 + fr;
            const int sR = swz(row);
#pragma unroll
            for (int ks=0;ks<2;ks++){
                const short8 vf = *(const short8*)(Vlds + row*64 + (((ks*4+g) ^ sR)<<3));
                o[dt] = __builtin_amdgcn_mfma_f32_16x16x32_bf16(pa[ks], vf, o[dt], 0,0,0);
            }
        }
        __syncthreads();
    }

    float inv[4];
#pragma unroll
    for (int r=0;r<4;r++) inv[r] = 1.0f / l_run[r];
#pragma unroll
    for (int dt=0;dt<8;dt++){
#pragma unroll
        for (int r=0;r<4;r++){
            const int q = wq + 4*g + r;
            const int d = dt*16 + fr;
            Y[(size_t)(b*TT + q)*NE + h*HD + d] = f2bfu(o[dt][r]*inv[r]);
        }
    }
}

// ---------------- launch ----------------
extern "C" void kernel_launch(void* const* d_in, const int* in_sizes, int n_in,
                              void* d_out, int out_size, void* d_ws, size_t ws_size,
                              hipStream_t stream)
{
    const float* x      = (const float*)d_in[0];
    const float* w_attn = (const float*)d_in[1];
    const float* w_proj = (const float*)d_in[2];
    const float* pk0 = (const float*)d_in[3];
    const float* pv0 = (const float*)d_in[4];
    const float* pk1 = (const float*)d_in[5];
    const float* pv1 = (const float*)d_in[6];
    const float* pk2 = (const float*)d_in[7];
    const float* pv2 = (const float*)d_in[8];
    const float* pk3 = (const float*)d_in[9];
    const float* pv3 = (const float*)d_in[10];

    float* outY = (float*)d_out;
    float* outK = outY + (size_t)MM*NE;
    float* outV = outK + (size_t)MM*NE;

    char* w = (char*)d_ws;
    ushort* x_bf   = (ushort*)(w);              //  32 MiB; reused as vtS (24 MiB) after gemm1
    ushort* wa_bf  = (ushort*)(w + 33554432);   //  24 MiB; reused as vtC (8 MiB) after gemm1
    ushort* wp_bf  = (ushort*)(w + 58720256);   //   8 MiB; holds kc first, w_proj bf16 after attn
    ushort* qkv_bf = (ushort*)(w + 67108864);   //  96 MiB
    ushort* y_bf   = (ushort*)(w + 167772160);  //  32 MiB  (total 192 MiB)
    ushort* kc     = wp_bf;                     // cross-K bf16 (dead before wp cvt)
    ushort* vtS    = x_bf;                      // self-V^T (written after gemm1)
    ushort* vtC    = wa_bf;                     // cross-V^T (written after gemm1)

    cvt_f32_bf16<<<2048, 256, 0, stream>>>(x,      x_bf,  MM*NE/4);
    cvt_f32_bf16<<<2048, 256, 0, stream>>>(w_attn, wa_bf, NQKV*NE/4);

    kc_cvt<<<dim3(128,16), 256, 0, stream>>>(pk0, pk1, pk2, pk3, kc);

    gemm_bt<1><<<dim3(NQKV/128, MM/128), 256, 0, stream>>>(
        x_bf, wa_bf, qkv_bf, nullptr, outK, outV, NQKV, NE);

    // after gemm1: x_bf and wa_bf are dead -> safe to overwrite via stream order
    vt_self_k<<<dim3(8,16,48), 256, 0, stream>>>(qkv_bf, vtS);
    vt_cross_k<<<dim3(8,16,16), 256, 0, stream>>>(pv0, pv1, pv2, pv3, vtC);

    attn2<<<BB*NH*(TT/64), 256, 0, stream>>>(qkv_bf, kc, vtS, vtC, y_bf);

    cvt_f32_bf16<<<1024, 256, 0, stream>>>(w_proj, wp_bf, NE*NE/4);

    gemm_bt<0><<<dim3(NE/128, MM/128), 256, 0, stream>>>(
        y_bf, wp_bf, nullptr, outY, nullptr, nullptr, NE, NE);
}